// Round 2
// baseline (544.186 us; speedup 1.0000x reference)
//
#include <hip/hip_runtime.h>
#include <stdint.h>

#define NBOX 25200
#define NCH  16
#define TOPK 1024
#define NTH  1024
#define NBUCK 4096
#define CAP  2048        // sort capacity (top-1024 + cutoff-bucket slack)
#define LISTCAP 12288    // per-image candidate list capacity (exp ~10165, +27 sigma)
#define K1_SLICES 16
#define K1_TH 256
#define ROWS_PER_SLICE (NBOX / K1_SLICES)   // 1575

// ---------------- Kernel 1: score scan + candidate append (full-GPU) ----------------
__global__ __launch_bounds__(K1_TH) void score_kernel(const float* __restrict__ x,
                                                      unsigned long long* __restrict__ keys,
                                                      uint32_t* __restrict__ cnts) {
  const int img = blockIdx.x >> 4;
  const int slice = blockIdx.x & (K1_SLICES - 1);
  const int t = threadIdx.x;
  const int lane = t & 63;
  const float* __restrict__ xb = x + (size_t)img * NBOX * NCH;
  unsigned long long* __restrict__ kl = keys + (size_t)img * LISTCAP;

  const int r_end = (slice + 1) * ROWS_PER_SLICE;
  for (int r = slice * ROWS_PER_SLICE + t; r < r_end; r += K1_TH) {
    const float obj = xb[(size_t)r * NCH + 4];
    const float cls = xb[(size_t)r * NCH + 15];
    const float p = obj * cls;                 // exact ref arithmetic
    const bool has = (p > 0.25f);
    const unsigned long long m = __ballot(has);
    if (m) {
      const int leader = __ffsll((long long)m) - 1;
      const int myoff = __popcll(m & ((1ull << lane) - 1ull));
      uint32_t base = 0;
      if (lane == leader) base = atomicAdd(&cnts[img], (uint32_t)__popcll(m));
      base = (uint32_t)__shfl((int)base, leader);
      if (has) {
        const uint32_t idx = base + (uint32_t)myoff;
        if (idx < LISTCAP)
          kl[idx] = ((unsigned long long)__float_as_uint(p) << 32) |
                    (unsigned long long)(0xFFFFFFFFu - (uint32_t)r);
      }
    }
  }
}

// ---------------- Kernel 2: select + sort + NMS (one block per image) ----------------
union Smem {
  struct { uint32_t hist[NBUCK]; uint32_t coarse[NTH]; } a;   // 20 KB
  struct { unsigned long long keys[CAP]; } b;                 // 16 KB
  struct { float bx1[TOPK], by1[TOPK], bx2[TOPK], by2[TOPK]; uint32_t keep[TOPK]; } c; // 20 KB
};

__device__ __forceinline__ uint32_t bucket_of(uint32_t bits) {
  // score in (0.25, 1): bits in [0x3E800001, 0x3F800000); monotonic in value
  uint32_t bk = (bits - 0x3E800001u) >> 12;
  return bk > (NBUCK - 1u) ? (NBUCK - 1u) : bk;
}

__global__ __launch_bounds__(NTH, 1) void nms_kernel(const float* __restrict__ x,
                                                     const unsigned long long* __restrict__ keys,
                                                     const uint32_t* __restrict__ cnts,
                                                     float* __restrict__ out) {
  __shared__ Smem sm;
  __shared__ int s_g, s_cut, s_cnt;
  __shared__ unsigned long long s_acc;

  const int t = threadIdx.x;
  const int b = blockIdx.x;
  const float* __restrict__ xb = x + (size_t)b * NBOX * NCH;
  const unsigned long long* __restrict__ kl = keys + (size_t)b * LISTCAP;
  int cnt = (int)cnts[b];
  if (cnt > LISTCAP) cnt = LISTCAP;

  // ---- Phase 1: histogram over candidate score bits
  for (int j = t; j < NBUCK; j += NTH) sm.a.hist[j] = 0u;
  __syncthreads();
  for (int j = t; j < cnt; j += NTH)
    atomicAdd(&sm.a.hist[bucket_of((uint32_t)(kl[j] >> 32))], 1u);
  __syncthreads();

  // ---- Phase 2: cutoff = largest bucket c with suffix-count(c) >= TOPK
  {
    const uint32_t cs = sm.a.hist[4 * t] + sm.a.hist[4 * t + 1] +
                        sm.a.hist[4 * t + 2] + sm.a.hist[4 * t + 3];
    __syncthreads();
    sm.a.coarse[t] = cs;
  }
  __syncthreads();
  for (int off = 1; off < NTH; off <<= 1) {   // Hillis-Steele suffix scan
    uint32_t v = sm.a.coarse[t];
    if (t + off < NTH) v += sm.a.coarse[t + off];
    __syncthreads();
    sm.a.coarse[t] = v;
    __syncthreads();
  }
  if (t == 0) s_g = -1;
  __syncthreads();
  {
    const uint32_t suf = sm.a.coarse[t];
    const uint32_t sufn = (t + 1 < NTH) ? sm.a.coarse[t + 1] : 0u;
    if (suf >= TOPK && (t == NTH - 1 || sufn < TOPK)) s_g = t;
  }
  __syncthreads();
  if (t == 0) {
    int c = 0;
    const int g = s_g;
    if (g >= 0) {
      uint32_t S = sm.a.coarse[g];
      c = 4 * g;
      for (int j = 0; j < 3; ++j) {
        const uint32_t h = sm.a.hist[4 * g + j];
        if (S - h >= TOPK) { S -= h; ++c; } else break;
      }
    }
    s_cut = c;
    s_cnt = 0;
  }
  __syncthreads();
  const uint32_t cut = (uint32_t)s_cut;

  // ---- Phase 3: compact candidate keys >= cutoff bucket into LDS
  for (int j = t; j < cnt; j += NTH) {
    const unsigned long long key = kl[j];
    if (bucket_of((uint32_t)(key >> 32)) >= cut) {
      const int pos = atomicAdd(&s_cnt, 1);
      if (pos < CAP) sm.b.keys[pos] = key;
    }
  }
  __syncthreads();
  {
    int M = s_cnt; if (M > CAP) M = CAP;
    for (int j = t; j < CAP; j += NTH) if (j >= M) sm.b.keys[j] = 0ull;
  }
  __syncthreads();

  // ---- Phase 4: bitonic sort 2048 keys, descending
  for (int k2 = 2; k2 <= CAP; k2 <<= 1) {
    for (int j = k2 >> 1; j > 0; j >>= 1) {
      const int i = ((t & ~(j - 1)) << 1) | (t & (j - 1));
      const int l = i | j;
      const unsigned long long a = sm.b.keys[i];
      const unsigned long long bb = sm.b.keys[l];
      const bool dosw = ((i & k2) == 0) ? (a < bb) : (a > bb);
      if (dosw) { sm.b.keys[i] = bb; sm.b.keys[l] = a; }
      __syncthreads();
    }
  }

  // ---- Phase 5: take top-1024, gather rows, boxes to LDS
  const unsigned long long mykey = sm.b.keys[t];
  __syncthreads();   // before union reuse as .c

  const uint32_t sbits = (uint32_t)(mykey >> 32);
  const int src = (int)(0xFFFFFFFFu - (uint32_t)(mykey & 0xFFFFFFFFull));
  const bool valid = (sbits != 0u);
  const float conf = valid ? __uint_as_float(sbits) : 0.0f;

  float x1 = 0.f, y1 = 0.f, x2 = 0.f, y2 = 0.f;
  float lm0=0.f,lm1=0.f,lm2=0.f,lm3=0.f,lm4=0.f,lm5=0.f,lm6=0.f,lm7=0.f,lm8=0.f,lm9=0.f;
  if (valid) {
    const float4* rp = (const float4*)(xb + (size_t)src * NCH);
    const float4 q0 = rp[0], q1 = rp[1], q2 = rp[2], q3 = rp[3];
    x1 = q0.x - q0.z * 0.5f;
    y1 = q0.y - q0.w * 0.5f;
    x2 = q0.x + q0.z * 0.5f;
    y2 = q0.y + q0.w * 0.5f;
    lm0 = q1.y; lm1 = q1.z; lm2 = q1.w;
    lm3 = q2.x; lm4 = q2.y; lm5 = q2.z; lm6 = q2.w;
    lm7 = q3.x; lm8 = q3.y; lm9 = q3.z;
  }
  sm.c.bx1[t] = x1; sm.c.by1[t] = y1; sm.c.bx2[t] = x2; sm.c.by2[t] = y2;
  sm.c.keep[t] = valid ? 1u : 0u;
  __syncthreads();

  // ---- Phase 6: tiled greedy NMS (equivalent to sequential fori_loop)
  const float myarea = fmaxf(x2 - x1, 0.f) * fmaxf(y2 - y1, 0.f);
  uint32_t mykeep = valid ? 1u : 0u;

  for (int tile = 0; tile < TOPK / 64; ++tile) {
    if (t < 64) {
      const int gi = tile * 64 + t;
      const float ax1 = sm.c.bx1[gi], ay1 = sm.c.by1[gi];
      const float ax2 = sm.c.bx2[gi], ay2 = sm.c.by2[gi];
      uint32_t kb = sm.c.keep[gi];
      const float aarea = fmaxf(ax2 - ax1, 0.f) * fmaxf(ay2 - ay1, 0.f);
      for (int i = 0; i < 63; ++i) {
        const unsigned long long bal = __ballot(kb != 0u);
        if ((bal >> i) & 1ull) {                      // wave-uniform
          const float ix1 = __shfl(ax1, i);
          const float iy1 = __shfl(ay1, i);
          const float ix2 = __shfl(ax2, i);
          const float iy2 = __shfl(ay2, i);
          const float ia  = __shfl(aarea, i);
          if (t > i && kb) {
            const float iw = fmaxf(fminf(ax2, ix2) - fmaxf(ax1, ix1), 0.f);
            const float ih = fmaxf(fminf(ay2, iy2) - fmaxf(ay1, iy1), 0.f);
            const float inter = iw * ih;
            const float uni = ia + aarea - inter;     // area_i + area_j, ref order
            if (inter / (uni + 1e-9f) > 0.45f) kb = 0u;
          }
        }
      }
      sm.c.keep[gi] = kb;
      const unsigned long long fin = __ballot(kb != 0u);
      if (t == 0) s_acc = fin;
    }
    __syncthreads();
    const unsigned long long am = s_acc;
    if (t >= (tile + 1) * 64 && mykeep) {
      for (int i = 0; i < 64; ++i) {
        if ((am >> i) & 1ull) {
          const int gi = tile * 64 + i;
          const float ix1 = sm.c.bx1[gi], iy1 = sm.c.by1[gi];
          const float ix2 = sm.c.bx2[gi], iy2 = sm.c.by2[gi];
          const float ia = fmaxf(ix2 - ix1, 0.f) * fmaxf(iy2 - iy1, 0.f);
          const float iw = fmaxf(fminf(x2, ix2) - fmaxf(x1, ix1), 0.f);
          const float ih = fmaxf(fminf(y2, iy2) - fmaxf(y1, iy1), 0.f);
          const float inter = iw * ih;
          const float uni = ia + myarea - inter;
          if (inter / (uni + 1e-9f) > 0.45f) { mykeep = 0u; break; }
        }
      }
      if (!mykeep) sm.c.keep[t] = 0u;
    }
    __syncthreads();
  }

  // ---- Phase 7: write output row (16 floats), multiplied by keep
  const float m = sm.c.keep[t] ? 1.0f : 0.0f;
  float* __restrict__ ob = out + ((size_t)b * TOPK + (size_t)t) * NCH;
  float4* op = (float4*)ob;
  op[0] = make_float4(x1 * m, y1 * m, x2 * m, y2 * m);
  op[1] = make_float4(conf * m, lm0 * m, lm1 * m, lm2 * m);
  op[2] = make_float4(lm3 * m, lm4 * m, lm5 * m, lm6 * m);
  op[3] = make_float4(lm7 * m, lm8 * m, lm9 * m, 0.0f);
}

extern "C" void kernel_launch(void* const* d_in, const int* in_sizes, int n_in,
                              void* d_out, int out_size, void* d_ws, size_t ws_size,
                              hipStream_t stream) {
  const float* x = (const float*)d_in[0];
  float* out = (float*)d_out;
  uint32_t* cnts = (uint32_t*)d_ws;                                   // 64 * u32
  unsigned long long* keys = (unsigned long long*)((char*)d_ws + 256); // 64 * LISTCAP * u64

  hipMemsetAsync(d_ws, 0, 256, stream);  // zero per-image counters (ws is re-poisoned)
  score_kernel<<<dim3(64 * K1_SLICES), dim3(K1_TH), 0, stream>>>(x, keys, cnts);
  nms_kernel<<<dim3(64), dim3(NTH), 0, stream>>>(x, keys, cnts, out);
}

// Round 3
// 350.071 us; speedup vs baseline: 1.5545x; 1.5545x over previous
//
#include <hip/hip_runtime.h>
#include <stdint.h>

#define NBOX 25200
#define NCH  16
#define TOPK 1024
#define NTH  1024
#define NBUCK 4096
#define CAP  2048        // candidate capacity after cutoff (expected ~1027)
#define LISTCAP 12288    // per-image candidate list capacity (exp ~10165)
#define K1_SLICES 16
#define K1_TH 256
#define ROWS_PER_SLICE (NBOX / K1_SLICES)   // 1575
#define K1_ITERS 7                          // ceil(1575/256)

// exact threshold: RN_f32(inter/den) > 0.45f  <=>  (double)inter > M45*(double)den
// (0.45f = 0x3EE66666, even mantissa -> midpoint ties down; 25b x 24b product exact)
#define M45 ((double)0.45f + 0x1p-26)

__device__ __forceinline__ unsigned long long make_key(float p, uint32_t r) {
  return ((unsigned long long)__float_as_uint(p) << 32) |
         (unsigned long long)(0xFFFFFFFFu - r);
}

__device__ __forceinline__ uint32_t bucket_of(uint32_t bits) {
  uint32_t bk = (bits - 0x3E800001u) >> 12;
  return bk > (NBUCK - 1u) ? (NBUCK - 1u) : bk;
}

// ---------------- Kernel 1: score scan + candidate append (full-GPU) ----------------
__global__ __launch_bounds__(K1_TH) void score_kernel(const float* __restrict__ x,
                                                      unsigned long long* __restrict__ keys,
                                                      uint32_t* __restrict__ cnts) {
  const int img = blockIdx.x >> 4;
  const int slice = blockIdx.x & (K1_SLICES - 1);
  const int t = threadIdx.x;
  const int lane = t & 63;
  const float* __restrict__ xb = x + (size_t)img * NBOX * NCH;
  unsigned long long* __restrict__ kl = keys + (size_t)img * LISTCAP;
  const int row0 = slice * ROWS_PER_SLICE;

  // all loads first (pipelined), one score per unrolled slot
  float p[K1_ITERS];
  uint32_t mask = 0;
#pragma unroll
  for (int j = 0; j < K1_ITERS; ++j) {
    const int rr = t + j * K1_TH;
    float v = 0.0f;
    if (rr < ROWS_PER_SLICE) {
      const size_t ro = (size_t)(row0 + rr) * NCH;
      v = xb[ro + 4] * xb[ro + 15];          // exact ref arithmetic
      if (v > 0.25f) mask |= (1u << j);
    }
    p[j] = v;
  }

  // wave prefix-sum of per-lane counts, ONE atomic per wave
  const int cntl = __popc(mask);
  uint32_t inc = (uint32_t)cntl;
#pragma unroll
  for (int off = 1; off < 64; off <<= 1) {
    const uint32_t o = __shfl_up(inc, off);
    if (lane >= off) inc += o;
  }
  const uint32_t wtotal = __shfl(inc, 63);
  uint32_t base = 0;
  if (lane == 63 && wtotal) base = atomicAdd(&cnts[img], wtotal);
  base = (uint32_t)__shfl((int)base, 63);

  uint32_t pos = base + (inc - (uint32_t)cntl);
#pragma unroll
  for (int j = 0; j < K1_ITERS; ++j) {
    if ((mask >> j) & 1u) {
      if (pos < LISTCAP)
        kl[pos] = make_key(p[j], (uint32_t)(row0 + t + j * K1_TH));
      ++pos;
    }
  }
}

// ---------------- Kernel 2: select + rank + NMS (one block per image) ----------------
__global__ __launch_bounds__(NTH, 1) void nms_kernel(const float* __restrict__ x,
                                                     const unsigned long long* __restrict__ keys,
                                                     const uint32_t* __restrict__ cnts,
                                                     float* __restrict__ out) {
  __shared__ uint32_t s_hist[NBUCK];                 // 16 KB
  __shared__ unsigned long long s_keys[CAP];         // 16 KB
  __shared__ unsigned long long s_sorted[TOPK];      // 8 KB
  __shared__ float4 s_box[TOPK];                     // 16 KB
  __shared__ float s_area[TOPK];                     // 4 KB
  __shared__ uint32_t s_wsum[16];
  __shared__ int s_g, s_cut, s_cnt;
  __shared__ uint32_t s_S;
  __shared__ unsigned long long s_acc;

  const int t = threadIdx.x;
  const int b = blockIdx.x;
  const int lane = t & 63;
  const int wid = t >> 6;
  const float* __restrict__ xb = x + (size_t)b * NBOX * NCH;
  const unsigned long long* __restrict__ kl = keys + (size_t)b * LISTCAP;
  int cnt = (int)cnts[b];
  if (cnt > LISTCAP) cnt = LISTCAP;

  // ---- Phase 1: init + histogram of candidate score bits
  s_sorted[t] = 0ull;                                // init scatter target early
#pragma unroll
  for (int j = 0; j < NBUCK / NTH; ++j) s_hist[t + j * NTH] = 0u;
  if (t == 0) { s_g = -1; s_cnt = 0; }
  __syncthreads();
  for (int j0 = 0; j0 < cnt; j0 += NTH) {
    const int j = j0 + t;
    if (j < cnt) atomicAdd(&s_hist[bucket_of((uint32_t)(kl[j] >> 32))], 1u);
  }
  __syncthreads();

  // ---- Phase 2: cutoff bucket via wave-level suffix scans (3 barriers)
  const uint32_t cs = s_hist[4 * t] + s_hist[4 * t + 1] +
                      s_hist[4 * t + 2] + s_hist[4 * t + 3];
  uint32_t v = cs;
#pragma unroll
  for (int off = 1; off < 64; off <<= 1) {           // inclusive suffix within wave
    const uint32_t o = __shfl_down(v, off);
    if (lane + off < 64) v += o;
  }
  if (lane == 0) s_wsum[wid] = v;
  __syncthreads();
  uint32_t tail = 0;
#pragma unroll
  for (int w = 0; w < 16; ++w) if (w > wid) tail += s_wsum[w];
  const uint32_t S = v + tail;                        // inclusive suffix at t
  if (S >= TOPK && (S - cs) < TOPK) { s_g = t; s_S = S; }
  __syncthreads();
  if (t == 0) {
    int c = 0;
    if (s_g >= 0) {
      uint32_t Sv = s_S;
      c = 4 * s_g;
      for (int j = 0; j < 3; ++j) {
        const uint32_t h = s_hist[4 * s_g + j];
        if (Sv - h >= TOPK) { Sv -= h; ++c; } else break;
      }
    }
    s_cut = c;
  }
  __syncthreads();
  const uint32_t cut = (uint32_t)s_cut;

  // ---- Phase 3: compact keys >= cutoff into LDS (wave-aggregated append)
  for (int j0 = 0; j0 < cnt; j0 += NTH) {
    const int j = j0 + t;
    unsigned long long key = 0ull;
    bool has = false;
    if (j < cnt) {
      key = kl[j];
      has = bucket_of((uint32_t)(key >> 32)) >= cut;
    }
    const unsigned long long mm = __ballot(has);
    if (mm) {
      const int leader = __ffsll((long long)mm) - 1;
      const int off = (int)__popcll(mm & ((1ull << lane) - 1ull));
      int bpos = 0;
      if (lane == leader) bpos = atomicAdd(&s_cnt, (int)__popcll(mm));
      bpos = __shfl(bpos, leader);
      if (has && bpos + off < CAP) s_keys[bpos + off] = key;
    }
  }
  __syncthreads();

  // ---- Phase 4: exact rank by counting (broadcast reads, barrier-free loop)
  int M = s_cnt; if (M > CAP) M = CAP;
  const unsigned long long k0 = (t < M) ? s_keys[t] : 0ull;
  int r0 = 0;
  {
    int j = 0;
    for (; j + 3 < M; j += 4) {
      const unsigned long long a0 = s_keys[j], a1 = s_keys[j + 1];
      const unsigned long long a2 = s_keys[j + 2], a3 = s_keys[j + 3];
      r0 += (int)(a0 > k0) + (int)(a1 > k0) + (int)(a2 > k0) + (int)(a3 > k0);
    }
    for (; j < M; ++j) r0 += (int)(s_keys[j] > k0);
  }
  unsigned long long k1 = 0ull; int r1 = 0;
  if (t + NTH < M) {                                  // only a few threads (M ~ 1027)
    k1 = s_keys[t + NTH];
    for (int j = 0; j < M; ++j) r1 += (int)(s_keys[j] > k1);
  }
  if (k0 && r0 < TOPK) s_sorted[r0] = k0;
  if (k1 && r1 < TOPK) s_sorted[r1] = k1;
  __syncthreads();

  // ---- Phase 5: gather rows of the top-1024, boxes+areas to LDS
  const unsigned long long mykey = s_sorted[t];
  const uint32_t sbits = (uint32_t)(mykey >> 32);
  const int src = (int)(0xFFFFFFFFu - (uint32_t)(mykey & 0xFFFFFFFFull));
  const bool valid = (sbits != 0u);
  const float conf = valid ? __uint_as_float(sbits) : 0.0f;

  float x1 = 0.f, y1 = 0.f, x2 = 0.f, y2 = 0.f;
  float lm0=0.f,lm1=0.f,lm2=0.f,lm3=0.f,lm4=0.f,lm5=0.f,lm6=0.f,lm7=0.f,lm8=0.f,lm9=0.f;
  if (valid) {
    const float4* rp = (const float4*)(xb + (size_t)src * NCH);
    const float4 q0 = rp[0], q1 = rp[1], q2 = rp[2], q3 = rp[3];
    x1 = q0.x - q0.z * 0.5f;
    y1 = q0.y - q0.w * 0.5f;
    x2 = q0.x + q0.z * 0.5f;
    y2 = q0.y + q0.w * 0.5f;
    lm0 = q1.y; lm1 = q1.z; lm2 = q1.w;
    lm3 = q2.x; lm4 = q2.y; lm5 = q2.z; lm6 = q2.w;
    lm7 = q3.x; lm8 = q3.y; lm9 = q3.z;
  }
  const float myarea = fmaxf(x2 - x1, 0.f) * fmaxf(y2 - y1, 0.f);
  s_box[t] = make_float4(x1, y1, x2, y2);
  s_area[t] = myarea;
  __syncthreads();

  // ---- Phase 6a: per-thread suppression mask vs own tile (pipelined, no barriers)
  uint32_t mykeep = valid ? 1u : 0u;
  unsigned long long lowmask = 0ull;
  {
    const int base = wid * 64;
    for (int i = 0; i < 64; ++i) {
      const float4 ob = s_box[base + i];              // broadcast read
      const float ia = s_area[base + i];
      const float iw = fmaxf(fminf(x2, ob.z) - fmaxf(x1, ob.x), 0.f);
      const float ih = fmaxf(fminf(y2, ob.w) - fmaxf(y1, ob.y), 0.f);
      const float inter = iw * ih;
      const float den = ((ia + myarea) - inter) + 1e-9f;
      if ((double)inter > M45 * (double)den) lowmask |= (1ull << i);
    }
    lowmask &= ((1ull << lane) - 1ull);               // only earlier in-tile boxes
  }

  // ---- Phase 6b: sequential greedy over 16 tiles
  for (int tile = 0; tile < TOPK / 64; ++tile) {
    if (wid == tile) {                                // register-only ballot closure
      for (int i = 0; i < 63; ++i) {
        const unsigned long long alive = __ballot(mykeep != 0u);
        if ((alive >> i) & 1ull)
          if ((lowmask >> i) & 1ull) mykeep = 0u;
      }
      const unsigned long long fin = __ballot(mykeep != 0u);
      if (lane == 0) s_acc = fin;
    }
    __syncthreads();
    const unsigned long long am = s_acc;
    if (wid > tile && mykeep) {                       // break-free masked apply
      const int base = tile * 64;
      unsigned long long sup = 0ull;
      for (int i = 0; i < 64; ++i) {
        const float4 ob = s_box[base + i];            // broadcast read
        const float ia = s_area[base + i];
        const float iw = fmaxf(fminf(x2, ob.z) - fmaxf(x1, ob.x), 0.f);
        const float ih = fmaxf(fminf(y2, ob.w) - fmaxf(y1, ob.y), 0.f);
        const float inter = iw * ih;
        const float den = ((ia + myarea) - inter) + 1e-9f;
        if ((double)inter > M45 * (double)den) sup |= (1ull << i);
      }
      if (am & sup) mykeep = 0u;
    }
    __syncthreads();
  }

  // ---- Phase 7: write output row
  const float m = mykeep ? 1.0f : 0.0f;
  float* __restrict__ ob = out + ((size_t)b * TOPK + (size_t)t) * NCH;
  float4* op = (float4*)ob;
  op[0] = make_float4(x1 * m, y1 * m, x2 * m, y2 * m);
  op[1] = make_float4(conf * m, lm0 * m, lm1 * m, lm2 * m);
  op[2] = make_float4(lm3 * m, lm4 * m, lm5 * m, lm6 * m);
  op[3] = make_float4(lm7 * m, lm8 * m, lm9 * m, 0.0f);
}

extern "C" void kernel_launch(void* const* d_in, const int* in_sizes, int n_in,
                              void* d_out, int out_size, void* d_ws, size_t ws_size,
                              hipStream_t stream) {
  const float* x = (const float*)d_in[0];
  float* out = (float*)d_out;
  uint32_t* cnts = (uint32_t*)d_ws;                                   // 64 * u32
  unsigned long long* keys = (unsigned long long*)((char*)d_ws + 256); // 64 * LISTCAP * u64

  hipMemsetAsync(d_ws, 0, 256, stream);
  score_kernel<<<dim3(64 * K1_SLICES), dim3(K1_TH), 0, stream>>>(x, keys, cnts);
  nms_kernel<<<dim3(64), dim3(NTH), 0, stream>>>(x, keys, cnts, out);
}

// Round 4
// 253.172 us; speedup vs baseline: 2.1495x; 1.3827x over previous
//
#include <hip/hip_runtime.h>
#include <stdint.h>

#define NBOX 25200
#define NCH  16
#define TOPK 1024
#define NTH  1024
#define NBUCK 4096
#define CAP  2048        // scatter capacity (expected M ~ 1027)
#define LISTCAP 12288    // per-image candidate list capacity (exp ~10165)
#define K1_SLICES 16
#define K1_TH 256
#define ROWS_PER_SLICE (NBOX / K1_SLICES)   // 1575
#define K1_ITERS 7                          // ceil(1575/256)

// exact threshold: RN_f32(inter/den) > 0.45f  <=>  (double)inter > M45*(double)den
// (0.45f = 0x3EE66666, even mantissa -> midpoint ties round down; 25b x 24b exact in f64)
#define M45 ((double)0.45f + 0x1p-26)

// ws layout
#define OFF_KEYS  256
#define OFF_BOXES (OFF_KEYS + 64 * LISTCAP * 8)          // 6291712, 16B aligned
#define OFF_MASKS (OFF_BOXES + 64 * TOPK * 16)           // 7340288, 8B aligned

__device__ __forceinline__ unsigned long long make_key(float p, uint32_t r) {
  return ((unsigned long long)__float_as_uint(p) << 32) |
         (unsigned long long)(0xFFFFFFFFu - r);
}

__device__ __forceinline__ uint32_t bucket_of(uint32_t bits) {
  uint32_t bk = (bits - 0x3E800001u) >> 12;
  return bk > (NBUCK - 1u) ? (NBUCK - 1u) : bk;
}

// ---------------- K1: score scan + candidate append (full-GPU) ----------------
__global__ __launch_bounds__(K1_TH) void score_kernel(const float* __restrict__ x,
                                                      unsigned long long* __restrict__ keys,
                                                      uint32_t* __restrict__ cnts) {
  const int img = blockIdx.x >> 4;
  const int slice = blockIdx.x & (K1_SLICES - 1);
  const int t = threadIdx.x;
  const int lane = t & 63;
  const float* __restrict__ xb = x + (size_t)img * NBOX * NCH;
  unsigned long long* __restrict__ kl = keys + (size_t)img * LISTCAP;
  const int row0 = slice * ROWS_PER_SLICE;

  float p[K1_ITERS];
  uint32_t mask = 0;
#pragma unroll
  for (int j = 0; j < K1_ITERS; ++j) {
    const int rr = t + j * K1_TH;
    float v = 0.0f;
    if (rr < ROWS_PER_SLICE) {
      const size_t ro = (size_t)(row0 + rr) * NCH;
      v = xb[ro + 4] * xb[ro + 15];          // exact ref arithmetic
      if (v > 0.25f) mask |= (1u << j);
    }
    p[j] = v;
  }

  const int cntl = __popc(mask);
  uint32_t inc = (uint32_t)cntl;
#pragma unroll
  for (int off = 1; off < 64; off <<= 1) {
    const uint32_t o = __shfl_up(inc, off);
    if (lane >= off) inc += o;
  }
  const uint32_t wtotal = __shfl(inc, 63);
  uint32_t base = 0;
  if (lane == 63 && wtotal) base = atomicAdd(&cnts[img], wtotal);
  base = (uint32_t)__shfl((int)base, 63);

  uint32_t pos = base + (inc - (uint32_t)cntl);
#pragma unroll
  for (int j = 0; j < K1_ITERS; ++j) {
    if ((mask >> j) & 1u) {
      if (pos < LISTCAP)
        kl[pos] = make_key(p[j], (uint32_t)(row0 + t + j * K1_TH));
      ++pos;
    }
  }
}

// ---------------- K2: select + bucket-scatter sort + gather (one block/image) ----------------
__global__ __launch_bounds__(NTH, 1) void select_kernel(const float* __restrict__ x,
                                                        const unsigned long long* __restrict__ keys,
                                                        const uint32_t* __restrict__ cnts,
                                                        float* __restrict__ out,
                                                        float4* __restrict__ boxes) {
  __shared__ uint32_t s_hist[NBUCK];                 // 16 KB (pristine counts)
  __shared__ uint32_t s_pos[NBUCK];                  // 16 KB (scatter cursors)
  __shared__ unsigned long long s_sorted[CAP];       // 16 KB
  __shared__ unsigned long long s_final[TOPK];       // 8 KB
  __shared__ uint32_t s_wsum[16];
  __shared__ int s_cut;

  const int t = threadIdx.x;
  const int b = blockIdx.x;
  const int lane = t & 63;
  const int wid = t >> 6;
  const float* __restrict__ xb = x + (size_t)b * NBOX * NCH;
  const unsigned long long* __restrict__ kl = keys + (size_t)b * LISTCAP;
  int cnt = (int)cnts[b];
  if (cnt > LISTCAP) cnt = LISTCAP;

  // ---- init + histogram
#pragma unroll
  for (int j = 0; j < NBUCK / NTH; ++j) s_hist[t + j * NTH] = 0u;
  s_final[t] = 0ull;
  if (t == 0) s_cut = 0;
  __syncthreads();
  for (int j = t; j < cnt; j += NTH)
    atomicAdd(&s_hist[bucket_of((uint32_t)(kl[j] >> 32))], 1u);
  __syncthreads();

  // ---- fine suffix scan over 4096 buckets (thread t owns quad 4t..4t+3)
  const uint32_t h0 = s_hist[4 * t], h1 = s_hist[4 * t + 1];
  const uint32_t h2 = s_hist[4 * t + 2], h3 = s_hist[4 * t + 3];
  const uint32_t qs = h0 + h1 + h2 + h3;
  uint32_t v = qs;
#pragma unroll
  for (int off = 1; off < 64; off <<= 1) {           // inclusive suffix within wave
    const uint32_t o = __shfl_down(v, off);
    if (lane + off < 64) v += o;
  }
  if (lane == 0) s_wsum[wid] = v;
  __syncthreads();
  uint32_t tail = 0;
#pragma unroll
  for (int w = 0; w < 16; ++w) if (w > wid) tail += s_wsum[w];
  const uint32_t after = (v - qs) + tail;            // sum of buckets after my quad
  const uint32_t e3 = after, e2 = after + h3, e1 = e2 + h2, e0 = e1 + h1;
  s_pos[4 * t] = e0; s_pos[4 * t + 1] = e1;
  s_pos[4 * t + 2] = e2; s_pos[4 * t + 3] = e3;
  // cutoff: largest bucket with inclusive suffix >= TOPK
  int cand = -1;
  if (e3 + h3 >= TOPK) cand = 4 * t + 3;
  else if (e2 + h2 >= TOPK) cand = 4 * t + 2;
  else if (e1 + h1 >= TOPK) cand = 4 * t + 1;
  else if (e0 + h0 >= TOPK) cand = 4 * t;
  if (cand >= 0) atomicMax(&s_cut, cand);
  __syncthreads();
  const int cut = s_cut;
  int M = (int)(s_pos[cut] + s_hist[cut]);           // # keys in buckets >= cut
  if (M > CAP) M = CAP;
  __syncthreads();                                   // all read M before cursors move

  // ---- scatter keys >= cut into bucket slices
  for (int j = t; j < cnt; j += NTH) {
    const unsigned long long key = kl[j];
    const uint32_t bk = bucket_of((uint32_t)(key >> 32));
    if ((int)bk >= cut) {
      const uint32_t pos = atomicAdd(&s_pos[bk], 1u);
      if (pos < CAP) s_sorted[pos] = key;
    }
  }
  __syncthreads();

  // ---- exact in-bucket rank (slices are tiny: ~1-3 keys)
  for (int p = t; p < M; p += NTH) {
    const unsigned long long key = s_sorted[p];
    const uint32_t bk = bucket_of((uint32_t)(key >> 32));
    int end = (int)s_pos[bk]; if (end > M) end = M;
    int start = end - (int)s_hist[bk]; if (start < 0) start = 0;
    int lr = 0;
    for (int q = start; q < end; ++q) lr += (int)(s_sorted[q] > key);
    const int fp = start + lr;
    if (fp < TOPK) s_final[fp] = key;
  }
  __syncthreads();

  // ---- gather rows of top-1024; write unscaled dets + boxes
  const unsigned long long mykey = s_final[t];
  const uint32_t sbits = (uint32_t)(mykey >> 32);
  const int src = (int)(0xFFFFFFFFu - (uint32_t)(mykey & 0xFFFFFFFFull));
  const bool valid = (sbits != 0u);
  const float conf = valid ? __uint_as_float(sbits) : 0.0f;

  float x1 = 0.f, y1 = 0.f, x2 = 0.f, y2 = 0.f;
  float lm0=0.f,lm1=0.f,lm2=0.f,lm3=0.f,lm4=0.f,lm5=0.f,lm6=0.f,lm7=0.f,lm8=0.f,lm9=0.f;
  if (valid) {
    const float4* rp = (const float4*)(xb + (size_t)src * NCH);
    const float4 q0 = rp[0], q1 = rp[1], q2 = rp[2], q3 = rp[3];
    x1 = q0.x - q0.z * 0.5f;
    y1 = q0.y - q0.w * 0.5f;
    x2 = q0.x + q0.z * 0.5f;
    y2 = q0.y + q0.w * 0.5f;
    lm0 = q1.y; lm1 = q1.z; lm2 = q1.w;
    lm3 = q2.x; lm4 = q2.y; lm5 = q2.z; lm6 = q2.w;
    lm7 = q3.x; lm8 = q3.y; lm9 = q3.z;
  }
  boxes[(size_t)b * TOPK + t] = make_float4(x1, y1, x2, y2);
  float4* op = (float4*)(out + ((size_t)b * TOPK + (size_t)t) * NCH);
  op[0] = make_float4(x1, y1, x2, y2);
  op[1] = make_float4(conf, lm0, lm1, lm2);
  op[2] = make_float4(lm3, lm4, lm5, lm6);
  op[3] = make_float4(lm7, lm8, lm9, 0.0f);
}

// ---------------- K2m: suppression bit-matrix, lower triangle (full-GPU) ----------------
// grid = 64 images x 40 slots; block = 256 thr; wave w handles word jw = wg*4+w of rowtile rt.
__global__ __launch_bounds__(256) void mask_kernel(const float4* __restrict__ boxes,
                                                   unsigned long long* __restrict__ masks) {
  const int img = blockIdx.x / 40;
  const int s = blockIdx.x % 40;
  int rt, wg;
  if (s < 4)        { rt = s;                wg = 0; }
  else if (s < 12)  { rt = 4 + ((s - 4) >> 1);  wg = (s - 4) & 1; }
  else if (s < 24)  { rt = 8 + (s - 12) / 3;    wg = (s - 12) % 3; }
  else              { rt = 12 + ((s - 24) >> 2); wg = (s - 24) & 3; }

  const int t = threadIdx.x;
  const int lane = t & 63;
  const int jw = wg * 4 + (t >> 6);

  __shared__ float4 s_rbox[64];
  if (t < 64) s_rbox[t] = boxes[(size_t)img * TOPK + rt * 64 + t];
  __syncthreads();
  if (jw > rt) return;                                // idle wave (uniform)

  const float4 cb = boxes[(size_t)img * TOPK + jw * 64 + lane];  // my column box
  const float ca = fmaxf(cb.z - cb.x, 0.f) * fmaxf(cb.w - cb.y, 0.f);

  unsigned long long myword = 0ull;
  for (int rl = 0; rl < 64; ++rl) {
    const float4 rb = s_rbox[rl];                     // broadcast row box
    const float ra = fmaxf(rb.z - rb.x, 0.f) * fmaxf(rb.w - rb.y, 0.f);
    const float iw = fmaxf(fminf(cb.z, rb.z) - fmaxf(cb.x, rb.x), 0.f);
    const float ih = fmaxf(fminf(cb.w, rb.w) - fmaxf(cb.y, rb.y), 0.f);
    const float inter = iw * ih;
    const float den = ((ca + ra) - inter) + 1e-9f;    // area_col + area_row, ref order
    const bool sup = (double)inter > M45 * (double)den;
    unsigned long long bal = __ballot(sup);
    if (jw == rt) bal &= ((1ull << rl) - 1ull);       // only cols < row on the diagonal
    if (lane == rl) myword = bal;
  }
  masks[((size_t)img * 16 + jw) * TOPK + rt * 64 + lane] = myword;
}

// ---------------- K3: greedy bit-chain closure + zero suppressed rows ----------------
__global__ __launch_bounds__(NTH, 1) void greedy_kernel(const unsigned long long* __restrict__ masks,
                                                        float* __restrict__ out) {
  __shared__ unsigned long long s_alive[16];
  const int t = threadIdx.x;
  const int b = blockIdx.x;
  const int lane = t & 63;
  const int wid = t >> 6;

  unsigned long long w[16];
#pragma unroll
  for (int jw = 0; jw < 16; ++jw)
    w[jw] = (jw <= wid) ? masks[((size_t)b * 16 + jw) * TOPK + t] : 0ull;

  bool keep = true;
  unsigned long long acc = 0ull;
  for (int tile = 0; tile < 16; ++tile) {
    if (wid == tile) {
      if (acc) keep = false;                          // killed by earlier tiles
      const unsigned long long diag = w[wid];
      for (int i = 0; i < 63; ++i) {                  // sequential in-tile greedy
        const unsigned long long alive = __ballot(keep);
        if (((alive >> i) & 1ull) && ((diag >> i) & 1ull)) keep = false;
      }
      const unsigned long long fin = __ballot(keep);
      if (lane == 0) s_alive[tile] = fin;
    }
    __syncthreads();
    if (wid > tile) acc |= (w[tile] & s_alive[tile]);
  }

  if (!keep) {
    float4* op = (float4*)(out + ((size_t)b * TOPK + (size_t)t) * NCH);
    const float4 z = make_float4(0.f, 0.f, 0.f, 0.f);
    op[0] = z; op[1] = z; op[2] = z; op[3] = z;
  }
}

extern "C" void kernel_launch(void* const* d_in, const int* in_sizes, int n_in,
                              void* d_out, int out_size, void* d_ws, size_t ws_size,
                              hipStream_t stream) {
  const float* x = (const float*)d_in[0];
  float* out = (float*)d_out;
  uint32_t* cnts = (uint32_t*)d_ws;
  unsigned long long* keys = (unsigned long long*)((char*)d_ws + OFF_KEYS);
  float4* boxes = (float4*)((char*)d_ws + OFF_BOXES);
  unsigned long long* masks = (unsigned long long*)((char*)d_ws + OFF_MASKS);

  hipMemsetAsync(d_ws, 0, 256, stream);
  score_kernel<<<dim3(64 * K1_SLICES), dim3(K1_TH), 0, stream>>>(x, keys, cnts);
  select_kernel<<<dim3(64), dim3(NTH), 0, stream>>>(x, keys, cnts, out, boxes);
  mask_kernel<<<dim3(64 * 40), dim3(256), 0, stream>>>(boxes, masks);
  greedy_kernel<<<dim3(64), dim3(NTH), 0, stream>>>(masks, out);
}

// Round 5
// 221.958 us; speedup vs baseline: 2.4518x; 1.1406x over previous
//
#include <hip/hip_runtime.h>
#include <stdint.h>

#define NBOX 25200
#define NCH  16
#define TOPK 1024
#define NTH  1024
#define NBUCK 4096
#define CAP  2048        // scatter capacity (expected M ~ 1027)
#define LISTCAP 12288    // per-image candidate list capacity (exp ~10165)
#define K1_SLICES 16
#define K1_TH 256
#define ROWS_PER_SLICE (NBOX / K1_SLICES)   // 1575
#define K1_ITERS 7                          // ceil(1575/256)

// exact threshold: RN_f32(inter/den) > 0.45f  <=>  (double)inter > M45*(double)den
// (0.45f = 0x3EE66666, even mantissa -> midpoint ties round down; 25b x 24b exact in f64)
#define M45 ((double)0.45f + 0x1p-26)

// ws layout
#define OFF_KEYS  256
#define OFF_BOXES (OFF_KEYS + 64 * LISTCAP * 8)          // 16B aligned
#define OFF_MASKS (OFF_BOXES + 64 * TOPK * 16)           // 8B aligned

__device__ __forceinline__ unsigned long long make_key(float p, uint32_t r) {
  return ((unsigned long long)__float_as_uint(p) << 32) |
         (unsigned long long)(0xFFFFFFFFu - r);
}

__device__ __forceinline__ uint32_t bucket_of(uint32_t bits) {
  uint32_t bk = (bits - 0x3E800001u) >> 12;
  return bk > (NBUCK - 1u) ? (NBUCK - 1u) : bk;
}

// ---------------- K1: score scan + candidate append (full-GPU) ----------------
__global__ __launch_bounds__(K1_TH) void score_kernel(const float* __restrict__ x,
                                                      unsigned long long* __restrict__ keys,
                                                      uint32_t* __restrict__ cnts) {
  const int img = blockIdx.x >> 4;
  const int slice = blockIdx.x & (K1_SLICES - 1);
  const int t = threadIdx.x;
  const int lane = t & 63;
  const float* __restrict__ xb = x + (size_t)img * NBOX * NCH;
  unsigned long long* __restrict__ kl = keys + (size_t)img * LISTCAP;
  const int row0 = slice * ROWS_PER_SLICE;

  float p[K1_ITERS];
  uint32_t mask = 0;
#pragma unroll
  for (int j = 0; j < K1_ITERS; ++j) {
    const int rr = t + j * K1_TH;
    float v = 0.0f;
    if (rr < ROWS_PER_SLICE) {
      const size_t ro = (size_t)(row0 + rr) * NCH;
      v = xb[ro + 4] * xb[ro + 15];          // exact ref arithmetic
      if (v > 0.25f) mask |= (1u << j);
    }
    p[j] = v;
  }

  const int cntl = __popc(mask);
  uint32_t inc = (uint32_t)cntl;
#pragma unroll
  for (int off = 1; off < 64; off <<= 1) {
    const uint32_t o = __shfl_up(inc, off);
    if (lane >= off) inc += o;
  }
  const uint32_t wtotal = __shfl(inc, 63);
  uint32_t base = 0;
  if (lane == 63 && wtotal) base = atomicAdd(&cnts[img], wtotal);
  base = (uint32_t)__shfl((int)base, 63);

  uint32_t pos = base + (inc - (uint32_t)cntl);
#pragma unroll
  for (int j = 0; j < K1_ITERS; ++j) {
    if ((mask >> j) & 1u) {
      if (pos < LISTCAP)
        kl[pos] = make_key(p[j], (uint32_t)(row0 + t + j * K1_TH));
      ++pos;
    }
  }
}

// ---------------- K2: select + bucket-scatter sort + gather (one block/image) ----------------
__global__ __launch_bounds__(NTH, 1) void select_kernel(const float* __restrict__ x,
                                                        const unsigned long long* __restrict__ keys,
                                                        const uint32_t* __restrict__ cnts,
                                                        float* __restrict__ out,
                                                        float4* __restrict__ boxes) {
  __shared__ uint32_t s_hist[NBUCK];                 // 16 KB (pristine counts)
  __shared__ uint32_t s_pos[NBUCK];                  // 16 KB (scatter cursors)
  __shared__ unsigned long long s_sorted[CAP];       // 16 KB
  __shared__ unsigned long long s_final[TOPK];       // 8 KB
  __shared__ uint32_t s_wsum[16];
  __shared__ int s_cut;

  const int t = threadIdx.x;
  const int b = blockIdx.x;
  const int lane = t & 63;
  const int wid = t >> 6;
  const float* __restrict__ xb = x + (size_t)b * NBOX * NCH;
  const unsigned long long* __restrict__ kl = keys + (size_t)b * LISTCAP;
  int cnt = (int)cnts[b];
  if (cnt > LISTCAP) cnt = LISTCAP;

  // ---- init + histogram
#pragma unroll
  for (int j = 0; j < NBUCK / NTH; ++j) s_hist[t + j * NTH] = 0u;
  s_final[t] = 0ull;
  if (t == 0) s_cut = 0;
  __syncthreads();
  for (int j = t; j < cnt; j += NTH)
    atomicAdd(&s_hist[bucket_of((uint32_t)(kl[j] >> 32))], 1u);
  __syncthreads();

  // ---- fine suffix scan over 4096 buckets (thread t owns quad 4t..4t+3)
  const uint32_t h0 = s_hist[4 * t], h1 = s_hist[4 * t + 1];
  const uint32_t h2 = s_hist[4 * t + 2], h3 = s_hist[4 * t + 3];
  const uint32_t qs = h0 + h1 + h2 + h3;
  uint32_t v = qs;
#pragma unroll
  for (int off = 1; off < 64; off <<= 1) {           // inclusive suffix within wave
    const uint32_t o = __shfl_down(v, off);
    if (lane + off < 64) v += o;
  }
  if (lane == 0) s_wsum[wid] = v;
  __syncthreads();
  uint32_t tail = 0;
#pragma unroll
  for (int w = 0; w < 16; ++w) if (w > wid) tail += s_wsum[w];
  const uint32_t after = (v - qs) + tail;            // sum of buckets after my quad
  const uint32_t e3 = after, e2 = after + h3, e1 = e2 + h2, e0 = e1 + h1;
  s_pos[4 * t] = e0; s_pos[4 * t + 1] = e1;
  s_pos[4 * t + 2] = e2; s_pos[4 * t + 3] = e3;
  int cand = -1;
  if (e3 + h3 >= TOPK) cand = 4 * t + 3;
  else if (e2 + h2 >= TOPK) cand = 4 * t + 2;
  else if (e1 + h1 >= TOPK) cand = 4 * t + 1;
  else if (e0 + h0 >= TOPK) cand = 4 * t;
  if (cand >= 0) atomicMax(&s_cut, cand);
  __syncthreads();
  const int cut = s_cut;
  int M = (int)(s_pos[cut] + s_hist[cut]);           // # keys in buckets >= cut
  if (M > CAP) M = CAP;
  __syncthreads();                                   // all read M before cursors move

  // ---- scatter keys >= cut into bucket slices
  for (int j = t; j < cnt; j += NTH) {
    const unsigned long long key = kl[j];
    const uint32_t bk = bucket_of((uint32_t)(key >> 32));
    if ((int)bk >= cut) {
      const uint32_t pos = atomicAdd(&s_pos[bk], 1u);
      if (pos < CAP) s_sorted[pos] = key;
    }
  }
  __syncthreads();

  // ---- exact in-bucket rank (slices are tiny: ~1-3 keys)
  for (int p = t; p < M; p += NTH) {
    const unsigned long long key = s_sorted[p];
    const uint32_t bk = bucket_of((uint32_t)(key >> 32));
    int end = (int)s_pos[bk]; if (end > M) end = M;
    int start = end - (int)s_hist[bk]; if (start < 0) start = 0;
    int lr = 0;
    for (int q = start; q < end; ++q) lr += (int)(s_sorted[q] > key);
    const int fp = start + lr;
    if (fp < TOPK) s_final[fp] = key;
  }
  __syncthreads();

  // ---- gather rows of top-1024; write unscaled dets + boxes
  const unsigned long long mykey = s_final[t];
  const uint32_t sbits = (uint32_t)(mykey >> 32);
  const int src = (int)(0xFFFFFFFFu - (uint32_t)(mykey & 0xFFFFFFFFull));
  const bool valid = (sbits != 0u);
  const float conf = valid ? __uint_as_float(sbits) : 0.0f;

  float x1 = 0.f, y1 = 0.f, x2 = 0.f, y2 = 0.f;
  float lm0=0.f,lm1=0.f,lm2=0.f,lm3=0.f,lm4=0.f,lm5=0.f,lm6=0.f,lm7=0.f,lm8=0.f,lm9=0.f;
  if (valid) {
    const float4* rp = (const float4*)(xb + (size_t)src * NCH);
    const float4 q0 = rp[0], q1 = rp[1], q2 = rp[2], q3 = rp[3];
    x1 = q0.x - q0.z * 0.5f;
    y1 = q0.y - q0.w * 0.5f;
    x2 = q0.x + q0.z * 0.5f;
    y2 = q0.y + q0.w * 0.5f;
    lm0 = q1.y; lm1 = q1.z; lm2 = q1.w;
    lm3 = q2.x; lm4 = q2.y; lm5 = q2.z; lm6 = q2.w;
    lm7 = q3.x; lm8 = q3.y; lm9 = q3.z;
  }
  boxes[(size_t)b * TOPK + t] = make_float4(x1, y1, x2, y2);
  float4* op = (float4*)(out + ((size_t)b * TOPK + (size_t)t) * NCH);
  op[0] = make_float4(x1, y1, x2, y2);
  op[1] = make_float4(conf, lm0, lm1, lm2);
  op[2] = make_float4(lm3, lm4, lm5, lm6);
  op[3] = make_float4(lm7, lm8, lm9, 0.0f);
}

// ---------------- K2m: suppression bit-matrix, lower triangle (full-GPU) ----------------
// grid = 64 images x 40 slots; block = 256 thr; wave w handles word jw = wg*4+w of rowtile rt.
__global__ __launch_bounds__(256) void mask_kernel(const float4* __restrict__ boxes,
                                                   unsigned long long* __restrict__ masks) {
  const int img = blockIdx.x / 40;
  const int s = blockIdx.x % 40;
  int rt, wg;
  if (s < 4)        { rt = s;                wg = 0; }
  else if (s < 12)  { rt = 4 + ((s - 4) >> 1);  wg = (s - 4) & 1; }
  else if (s < 24)  { rt = 8 + (s - 12) / 3;    wg = (s - 12) % 3; }
  else              { rt = 12 + ((s - 24) >> 2); wg = (s - 24) & 3; }

  const int t = threadIdx.x;
  const int lane = t & 63;
  const int jw = wg * 4 + (t >> 6);

  __shared__ float4 s_rbox[64];
  if (t < 64) s_rbox[t] = boxes[(size_t)img * TOPK + rt * 64 + t];
  __syncthreads();
  if (jw > rt) return;                                // idle wave (uniform)

  const float4 cb = boxes[(size_t)img * TOPK + jw * 64 + lane];  // my column box
  const float ca = fmaxf(cb.z - cb.x, 0.f) * fmaxf(cb.w - cb.y, 0.f);

  unsigned long long myword = 0ull;
  for (int rl = 0; rl < 64; ++rl) {
    const float4 rb = s_rbox[rl];                     // broadcast row box
    const float ra = fmaxf(rb.z - rb.x, 0.f) * fmaxf(rb.w - rb.y, 0.f);
    const float iw = fmaxf(fminf(cb.z, rb.z) - fmaxf(cb.x, rb.x), 0.f);
    const float ih = fmaxf(fminf(cb.w, rb.w) - fmaxf(cb.y, rb.y), 0.f);
    const float inter = iw * ih;
    const float den = ((ca + ra) - inter) + 1e-9f;    // area_col + area_row, ref order
    const bool sup = (double)inter > M45 * (double)den;
    unsigned long long bal = __ballot(sup);
    if (jw == rt) bal &= ((1ull << rl) - 1ull);       // only cols < row on the diagonal
    if (lane == rl) myword = bal;
  }
  masks[((size_t)img * 16 + jw) * TOPK + rt * 64 + lane] = myword;
}

// ---------------- K3: greedy closure, victim-sparse chain (one block/image) ----------------
__global__ __launch_bounds__(NTH, 1) void greedy_kernel(const unsigned long long* __restrict__ masks,
                                                        float* __restrict__ out) {
  __shared__ unsigned long long s_alive[16];
  const int t = threadIdx.x;
  const int b = blockIdx.x;
  const int lane = t & 63;
  const int wid = t >> 6;

  // my diagonal-tile word: which earlier in-tile lanes suppress me (lower-masked)
  const unsigned long long diag = masks[((size_t)b * 16 + wid) * TOPK + t];

  bool keep = true;
  unsigned long long acc = 0ull;     // suppressors from earlier (finalized) tiles

  for (int tile = 0; tile < 16; ++tile) {
    // issue the cross-tile mask load before the barrier (independent of s_alive)
    unsigned long long mw = 0ull;
    if (wid > tile) mw = masks[((size_t)b * 16 + tile) * TOPK + t];

    if (wid == tile) {               // wave-uniform diagonal resolution
      if (acc) keep = false;
      // victim-sparse sequential greedy: only lanes with diag != 0 can flip
      unsigned long long vm = __ballot(diag != 0ull);
      while (vm) {
        const int vv = __ffsll((long long)vm) - 1;
        vm &= vm - 1ull;
        const unsigned long long alive = __ballot(keep);
        if (lane == vv && (alive & diag)) keep = false;
      }
      const unsigned long long fin = __ballot(keep);
      if (lane == 0) s_alive[tile] = fin;
    }
    __syncthreads();
    if (wid > tile) acc |= mw & s_alive[tile];
  }

  if (!keep) {
    float4* op = (float4*)(out + ((size_t)b * TOPK + (size_t)t) * NCH);
    const float4 z = make_float4(0.f, 0.f, 0.f, 0.f);
    op[0] = z; op[1] = z; op[2] = z; op[3] = z;
  }
}

extern "C" void kernel_launch(void* const* d_in, const int* in_sizes, int n_in,
                              void* d_out, int out_size, void* d_ws, size_t ws_size,
                              hipStream_t stream) {
  const float* x = (const float*)d_in[0];
  float* out = (float*)d_out;
  uint32_t* cnts = (uint32_t*)d_ws;
  unsigned long long* keys = (unsigned long long*)((char*)d_ws + OFF_KEYS);
  float4* boxes = (float4*)((char*)d_ws + OFF_BOXES);
  unsigned long long* masks = (unsigned long long*)((char*)d_ws + OFF_MASKS);

  hipMemsetAsync(d_ws, 0, 256, stream);
  score_kernel<<<dim3(64 * K1_SLICES), dim3(K1_TH), 0, stream>>>(x, keys, cnts);
  select_kernel<<<dim3(64), dim3(NTH), 0, stream>>>(x, keys, cnts, out, boxes);
  mask_kernel<<<dim3(64 * 40), dim3(256), 0, stream>>>(boxes, masks);
  greedy_kernel<<<dim3(64), dim3(NTH), 0, stream>>>(masks, out);
}

// Round 7
// 206.556 us; speedup vs baseline: 2.6346x; 1.0746x over previous
//
#include <hip/hip_runtime.h>
#include <stdint.h>

#define NBOX 25200
#define NCH  16
#define TOPK 1024
#define NTH  1024
#define NBUCK 4096
#define CAP  2048        // scatter capacity (expected M ~ 1027)
#define K1_SLICES 16
#define K1_TH 256
#define ROWS_PER_SLICE (NBOX / K1_SLICES)   // 1575
#define K1_ITERS 7                          // ceil(1575/256)
#define SEGCAP 1600      // >= ROWS_PER_SLICE: per-slice segment can never overflow

// exact threshold: RN_f32(inter/den) > 0.45f  <=>  (double)inter > M45*(double)den
// (0.45f = 0x3EE66666, even mantissa -> midpoint ties round down; 25b x 24b exact in f64)
#define M45 ((double)0.45f + 0x1p-26)

// ws layout (no zero-init required: counts always written before read, keys read < count)
// cnts: 64*16 u32 = 4096 B  -> keys MUST start at 4096 (round-6 crash: started at 256, overlapped)
#define OFF_KEYS  4096
#define OFF_BOXES (OFF_KEYS + 64 * K1_SLICES * SEGCAP * 8)   // 13111296, 16B aligned
#define OFF_MASKS (OFF_BOXES + 64 * TOPK * 16)               // 14159872, 8B aligned

__device__ __forceinline__ unsigned long long make_key(float p, uint32_t r) {
  return ((unsigned long long)__float_as_uint(p) << 32) |
         (unsigned long long)(0xFFFFFFFFu - r);
}

__device__ __forceinline__ uint32_t bucket_of(uint32_t bits) {
  uint32_t bk = (bits - 0x3E800001u) >> 12;
  return bk > (NBUCK - 1u) ? (NBUCK - 1u) : bk;
}

// ---------------- K1: score scan + deterministic segment append (full-GPU, no atomics) ----
__global__ __launch_bounds__(K1_TH) void score_kernel(const float* __restrict__ x,
                                                      unsigned long long* __restrict__ keys,
                                                      uint32_t* __restrict__ cnts) {
  const int img = blockIdx.x >> 4;
  const int slice = blockIdx.x & (K1_SLICES - 1);
  const int t = threadIdx.x;
  const int lane = t & 63;
  const int wid = t >> 6;                              // 4 waves per block
  const float* __restrict__ xb = x + (size_t)img * NBOX * NCH;
  unsigned long long* __restrict__ kl = keys + ((size_t)img * K1_SLICES + slice) * SEGCAP;
  const int row0 = slice * ROWS_PER_SLICE;

  float p[K1_ITERS];
  uint32_t mask = 0;
#pragma unroll
  for (int j = 0; j < K1_ITERS - 1; ++j) {             // 6 full iterations
    const size_t ro = (size_t)(row0 + t + j * K1_TH) * NCH;
    const float v = xb[ro + 4] * xb[ro + 15];          // exact ref arithmetic
    if (v > 0.25f) mask |= (1u << j);
    p[j] = v;
  }
  {                                                    // tail (rows 1536..1574)
    const int rr = t + (K1_ITERS - 1) * K1_TH;
    float v = 0.0f;
    if (rr < ROWS_PER_SLICE) {
      const size_t ro = (size_t)(row0 + rr) * NCH;
      v = xb[ro + 4] * xb[ro + 15];
      if (v > 0.25f) mask |= (1u << (K1_ITERS - 1));
    }
    p[K1_ITERS - 1] = v;
  }

  // wave-inclusive prefix of per-lane counts
  const int cntl = __popc(mask);
  uint32_t inc = (uint32_t)cntl;
#pragma unroll
  for (int off = 1; off < 64; off <<= 1) {
    const uint32_t o = __shfl_up(inc, off);
    if (lane >= off) inc += o;
  }
  const uint32_t wtotal = __shfl(inc, 63);

  __shared__ uint32_t s_wtot[4];
  if (lane == 63) s_wtot[wid] = wtotal;
  __syncthreads();
  uint32_t base = 0;
#pragma unroll
  for (int w = 0; w < 4; ++w) if (w < wid) base += s_wtot[w];

  uint32_t pos = base + (inc - (uint32_t)cntl);        // <= 1575 < SEGCAP: no bound check
#pragma unroll
  for (int j = 0; j < K1_ITERS; ++j) {
    if ((mask >> j) & 1u) {
      kl[pos] = make_key(p[j], (uint32_t)(row0 + t + j * K1_TH));
      ++pos;
    }
  }
  if (t == K1_TH - 1)                                  // wid==3, lane==63
    cnts[img * K1_SLICES + slice] = base + wtotal;
}

// ---------------- K2: select + bucket-scatter sort + gather (one block/image) ----------------
__global__ __launch_bounds__(NTH, 1) void select_kernel(const float* __restrict__ x,
                                                        const unsigned long long* __restrict__ keys,
                                                        const uint32_t* __restrict__ cnts,
                                                        float* __restrict__ out,
                                                        float4* __restrict__ boxes) {
  __shared__ uint32_t s_hist[NBUCK];                 // 16 KB (pristine counts)
  __shared__ uint32_t s_pos[NBUCK];                  // 16 KB (scatter cursors)
  __shared__ unsigned long long s_sorted[CAP];       // 16 KB
  __shared__ unsigned long long s_final[TOPK];       // 8 KB
  __shared__ uint32_t s_wsum[16];
  __shared__ uint32_t s_cnt16[K1_SLICES];
  __shared__ int s_cut;

  const int t = threadIdx.x;
  const int b = blockIdx.x;
  const int lane = t & 63;
  const int wid = t >> 6;
  const float* __restrict__ xb = x + (size_t)b * NBOX * NCH;
  const unsigned long long* __restrict__ kb0 = keys + (size_t)b * K1_SLICES * SEGCAP;

  // ---- init + histogram over 16 segments
#pragma unroll
  for (int j = 0; j < NBUCK / NTH; ++j) s_hist[t + j * NTH] = 0u;
  s_final[t] = 0ull;
  if (t < K1_SLICES) {
    uint32_t c = cnts[b * K1_SLICES + t];
    s_cnt16[t] = (c > SEGCAP) ? SEGCAP : c;          // defensive clamp
  }
  if (t == 0) s_cut = 0;
  __syncthreads();
#pragma unroll
  for (int s = 0; s < K1_SLICES; ++s) {
    const int cs_ = (int)s_cnt16[s];
    const unsigned long long* seg = kb0 + (size_t)s * SEGCAP;
    for (int j = t; j < cs_; j += NTH)
      atomicAdd(&s_hist[bucket_of((uint32_t)(seg[j] >> 32))], 1u);
  }
  __syncthreads();

  // ---- fine suffix scan over 4096 buckets (thread t owns quad 4t..4t+3)
  const uint32_t h0 = s_hist[4 * t], h1 = s_hist[4 * t + 1];
  const uint32_t h2 = s_hist[4 * t + 2], h3 = s_hist[4 * t + 3];
  const uint32_t qs = h0 + h1 + h2 + h3;
  uint32_t v = qs;
#pragma unroll
  for (int off = 1; off < 64; off <<= 1) {           // inclusive suffix within wave
    const uint32_t o = __shfl_down(v, off);
    if (lane + off < 64) v += o;
  }
  if (lane == 0) s_wsum[wid] = v;
  __syncthreads();
  uint32_t tail = 0;
#pragma unroll
  for (int w = 0; w < 16; ++w) if (w > wid) tail += s_wsum[w];
  const uint32_t after = (v - qs) + tail;            // sum of buckets after my quad
  const uint32_t e3 = after, e2 = after + h3, e1 = e2 + h2, e0 = e1 + h1;
  s_pos[4 * t] = e0; s_pos[4 * t + 1] = e1;
  s_pos[4 * t + 2] = e2; s_pos[4 * t + 3] = e3;
  int cand = -1;                                     // cutoff vote: wave-reduced max
  if (e3 + h3 >= TOPK) cand = 4 * t + 3;
  else if (e2 + h2 >= TOPK) cand = 4 * t + 2;
  else if (e1 + h1 >= TOPK) cand = 4 * t + 1;
  else if (e0 + h0 >= TOPK) cand = 4 * t;
  int wmax = cand;
#pragma unroll
  for (int off = 32; off > 0; off >>= 1) {
    const int o = __shfl_down(wmax, off);
    if (o > wmax) wmax = o;
  }
  if (lane == 0 && wmax >= 0) atomicMax(&s_cut, wmax);
  __syncthreads();
  const int cut = s_cut;
  int M = (int)(s_pos[cut] + s_hist[cut]);           // # keys in buckets >= cut
  if (M > CAP) M = CAP;
  __syncthreads();                                   // all read M before cursors move

  // ---- scatter keys >= cut into bucket slices
#pragma unroll
  for (int s = 0; s < K1_SLICES; ++s) {
    const int cs_ = (int)s_cnt16[s];
    const unsigned long long* seg = kb0 + (size_t)s * SEGCAP;
    for (int j = t; j < cs_; j += NTH) {
      const unsigned long long key = seg[j];
      const uint32_t bk = bucket_of((uint32_t)(key >> 32));
      if ((int)bk >= cut) {
        const uint32_t pos = atomicAdd(&s_pos[bk], 1u);
        if (pos < CAP) s_sorted[pos] = key;
      }
    }
  }
  __syncthreads();

  // ---- exact in-bucket rank (slices are tiny: ~1-3 keys)
  for (int p = t; p < M; p += NTH) {
    const unsigned long long key = s_sorted[p];
    const uint32_t bk = bucket_of((uint32_t)(key >> 32));
    int end = (int)s_pos[bk]; if (end > M) end = M;
    int start = end - (int)s_hist[bk]; if (start < 0) start = 0;
    int lr = 0;
    for (int q = start; q < end; ++q) lr += (int)(s_sorted[q] > key);
    const int fp = start + lr;
    if (fp < TOPK) s_final[fp] = key;
  }
  __syncthreads();

  // ---- gather rows of top-1024; write unscaled dets + boxes
  const unsigned long long mykey = s_final[t];
  const uint32_t sbits = (uint32_t)(mykey >> 32);
  const int src = (int)(0xFFFFFFFFu - (uint32_t)(mykey & 0xFFFFFFFFull));
  const bool valid = (sbits != 0u);
  const float conf = valid ? __uint_as_float(sbits) : 0.0f;

  float x1 = 0.f, y1 = 0.f, x2 = 0.f, y2 = 0.f;
  float lm0=0.f,lm1=0.f,lm2=0.f,lm3=0.f,lm4=0.f,lm5=0.f,lm6=0.f,lm7=0.f,lm8=0.f,lm9=0.f;
  if (valid) {
    const float4* rp = (const float4*)(xb + (size_t)src * NCH);
    const float4 q0 = rp[0], q1 = rp[1], q2 = rp[2], q3 = rp[3];
    x1 = q0.x - q0.z * 0.5f;
    y1 = q0.y - q0.w * 0.5f;
    x2 = q0.x + q0.z * 0.5f;
    y2 = q0.y + q0.w * 0.5f;
    lm0 = q1.y; lm1 = q1.z; lm2 = q1.w;
    lm3 = q2.x; lm4 = q2.y; lm5 = q2.z; lm6 = q2.w;
    lm7 = q3.x; lm8 = q3.y; lm9 = q3.z;
  }
  boxes[(size_t)b * TOPK + t] = make_float4(x1, y1, x2, y2);
  float4* op = (float4*)(out + ((size_t)b * TOPK + (size_t)t) * NCH);
  op[0] = make_float4(x1, y1, x2, y2);
  op[1] = make_float4(conf, lm0, lm1, lm2);
  op[2] = make_float4(lm3, lm4, lm5, lm6);
  op[3] = make_float4(lm7, lm8, lm9, 0.0f);
}

// ---------------- K2m: suppression bit-matrix, lower triangle (full-GPU) ----------------
// grid = 64 images x 40 slots; block = 256 thr; wave w handles word jw = wg*4+w of rowtile rt.
__global__ __launch_bounds__(256) void mask_kernel(const float4* __restrict__ boxes,
                                                   unsigned long long* __restrict__ masks) {
  const int img = blockIdx.x / 40;
  const int s = blockIdx.x % 40;
  int rt, wg;
  if (s < 4)        { rt = s;                wg = 0; }
  else if (s < 12)  { rt = 4 + ((s - 4) >> 1);  wg = (s - 4) & 1; }
  else if (s < 24)  { rt = 8 + (s - 12) / 3;    wg = (s - 12) % 3; }
  else              { rt = 12 + ((s - 24) >> 2); wg = (s - 24) & 3; }

  const int t = threadIdx.x;
  const int lane = t & 63;
  const int jw = wg * 4 + (t >> 6);

  __shared__ float4 s_rbox[64];
  __shared__ float s_rarea[64];
  if (t < 64) {
    const float4 rb = boxes[(size_t)img * TOPK + rt * 64 + t];
    s_rbox[t] = rb;
    s_rarea[t] = fmaxf(rb.z - rb.x, 0.f) * fmaxf(rb.w - rb.y, 0.f);
  }
  __syncthreads();
  if (jw > rt) return;                                // idle wave (uniform)

  const float4 cb = boxes[(size_t)img * TOPK + jw * 64 + lane];  // my column box
  const float ca = fmaxf(cb.z - cb.x, 0.f) * fmaxf(cb.w - cb.y, 0.f);

  unsigned long long myword = 0ull;
  for (int rl = 0; rl < 64; ++rl) {
    const float4 rb = s_rbox[rl];                     // broadcast row box
    const float ra = s_rarea[rl];                     // hoisted row area
    const float iw = fmaxf(fminf(cb.z, rb.z) - fmaxf(cb.x, rb.x), 0.f);
    const float ih = fmaxf(fminf(cb.w, rb.w) - fmaxf(cb.y, rb.y), 0.f);
    const float inter = iw * ih;
    const float den = ((ca + ra) - inter) + 1e-9f;    // area_col + area_row, ref order
    const bool sup = (double)inter > M45 * (double)den;
    unsigned long long bal = __ballot(sup);
    if (jw == rt) bal &= ((1ull << rl) - 1ull);       // only cols < row on the diagonal
    if (lane == rl) myword = bal;
  }
  masks[((size_t)img * 16 + jw) * TOPK + rt * 64 + lane] = myword;
}

// ---------------- K3: greedy closure, victim-sparse chain (one block/image) ----------------
__global__ __launch_bounds__(NTH, 1) void greedy_kernel(const unsigned long long* __restrict__ masks,
                                                        float* __restrict__ out) {
  __shared__ unsigned long long s_alive[16];
  const int t = threadIdx.x;
  const int b = blockIdx.x;
  const int lane = t & 63;
  const int wid = t >> 6;

  // my diagonal-tile word: which earlier in-tile lanes suppress me (lower-masked)
  const unsigned long long diag = masks[((size_t)b * 16 + wid) * TOPK + t];

  bool keep = true;
  unsigned long long acc = 0ull;     // suppressors from earlier (finalized) tiles

  for (int tile = 0; tile < 16; ++tile) {
    // issue the cross-tile mask load before the barrier (independent of s_alive)
    unsigned long long mw = 0ull;
    if (wid > tile) mw = masks[((size_t)b * 16 + tile) * TOPK + t];

    if (wid == tile) {               // wave-uniform diagonal resolution
      if (acc) keep = false;
      // victim-sparse sequential greedy: only lanes with diag != 0 can flip
      unsigned long long vm = __ballot(diag != 0ull);
      while (vm) {
        const int vv = __ffsll((long long)vm) - 1;
        vm &= vm - 1ull;
        const unsigned long long alive = __ballot(keep);
        if (lane == vv && (alive & diag)) keep = false;
      }
      const unsigned long long fin = __ballot(keep);
      if (lane == 0) s_alive[tile] = fin;
    }
    __syncthreads();
    if (wid > tile) acc |= mw & s_alive[tile];
  }

  if (!keep) {
    float4* op = (float4*)(out + ((size_t)b * TOPK + (size_t)t) * NCH);
    const float4 z = make_float4(0.f, 0.f, 0.f, 0.f);
    op[0] = z; op[1] = z; op[2] = z; op[3] = z;
  }
}

extern "C" void kernel_launch(void* const* d_in, const int* in_sizes, int n_in,
                              void* d_out, int out_size, void* d_ws, size_t ws_size,
                              hipStream_t stream) {
  const float* x = (const float*)d_in[0];
  float* out = (float*)d_out;
  uint32_t* cnts = (uint32_t*)d_ws;                                   // 64*16 u32, always written
  unsigned long long* keys = (unsigned long long*)((char*)d_ws + OFF_KEYS);
  float4* boxes = (float4*)((char*)d_ws + OFF_BOXES);
  unsigned long long* masks = (unsigned long long*)((char*)d_ws + OFF_MASKS);

  score_kernel<<<dim3(64 * K1_SLICES), dim3(K1_TH), 0, stream>>>(x, keys, cnts);
  select_kernel<<<dim3(64), dim3(NTH), 0, stream>>>(x, keys, cnts, out, boxes);
  mask_kernel<<<dim3(64 * 40), dim3(256), 0, stream>>>(boxes, masks);
  greedy_kernel<<<dim3(64), dim3(NTH), 0, stream>>>(masks, out);
}